// Round 1
// 264.838 us; speedup vs baseline: 1.0210x; 1.0210x over previous
//
#include <hip/hip_runtime.h>
#include <math.h>

// Attention pooling: context[b,d] = sum_t softmax_t( V . tanh(full[b,t,:]@W1 + last[b,:]@W2 + b1+b2) ) * full[b,t,d]
// B=32 T=2048 D=512 U=512, fp32 in/out. bV softmax-invariant -> dropped; b1+b2 folded into h2.
// R8: 2-phase double-buffered K-loop (guide T3 minimum recipe). BK 64->32 so A(2x16KB)+B(2x32KB)
//     double-buffer in LDS; next-step global_load_lds issued BEFORE current-step MFMA, single
//     __syncthreads per step whose vmcnt(0) drain is covered by the compute phase. Staging latency
//     (previously 100% exposed, kernel was latency-bound at 16% HBM / 12.6% MfmaUtil) now overlaps.
// ws (floats): h2 [B*U] @0, m_arr [512] @16384, l_arr [512] @16896, ctx [B*16*D] @17408,
//              W1T [U*D] bf16 @ float-offset 279552. Total ~1.64 MB.

#define BB 32
#define TT 2048
#define DD 512
#define UU 512
#define BKK 32
#define KSTEPS 16

typedef short bf16x8 __attribute__((ext_vector_type(8)));
typedef float f32x4  __attribute__((ext_vector_type(4)));

static __device__ __forceinline__ short f2bf(float f) {
    unsigned x = __float_as_uint(f);
    return (short)((x + 0x7fffu + ((x >> 16) & 1u)) >> 16);   // RNE
}

static __device__ __forceinline__ float fast_tanh(float x) {
    float e = __expf(2.f * x);
    return 1.f - 2.f * __builtin_amdgcn_rcpf(e + 1.f);
}

// ---------------- prep ----------------
// blocks [0,256): W1T[u][d] = bf16(W1[d][u]) tile-transposed
// blocks [256,384): h2 slice — block owns (b, 128-u-slice); threads d-split x2 + LDS combine
__global__ __launch_bounds__(256) void prep_kernel(const float* __restrict__ W1,
                                                   short* __restrict__ W1T,
                                                   const float* __restrict__ last,
                                                   const float* __restrict__ W2,
                                                   const float* __restrict__ b1,
                                                   const float* __restrict__ b2,
                                                   float* __restrict__ h2) {
    __shared__ float tile[32][33];
    __shared__ float ls[DD];
    __shared__ float part[256];
    const int bid = blockIdx.x;
    const int tid = threadIdx.x;
    if (bid < 256) {
        const int tr = (bid >> 4) << 5;   // d-block origin
        const int tc = (bid & 15) << 5;   // u-block origin
#pragma unroll
        for (int p = 0; p < 4; ++p) {
            const int r = p * 8 + (tid >> 5), c = tid & 31;
            tile[r][c] = W1[(size_t)(tr + r) * UU + tc + c];
        }
        __syncthreads();
#pragma unroll
        for (int p = 0; p < 4; ++p) {
            const int r = p * 8 + (tid >> 5), c = tid & 31;    // r=u-local, c=d-local
            W1T[(size_t)(tc + r) * DD + tr + c] = f2bf(tile[c][r]);
        }
    } else {
        const int b2i = bid - 256;
        const int b  = b2i >> 2;
        const int u0 = (b2i & 3) << 7;
        for (int i = tid; i < DD; i += 256) ls[i] = last[b * DD + i];
        __syncthreads();
        const int uu = tid & 127;
        const int dh = tid >> 7;
        float acc = 0.f;
#pragma unroll 8
        for (int d = dh * 256; d < dh * 256 + 256; ++d)
            acc += ls[d] * W2[d * UU + u0 + uu];
        part[tid] = acc;
        __syncthreads();
        if (tid < 128) {
            const int u = u0 + tid;
            h2[b * UU + u] = part[tid] + part[tid + 128] + b1[u] + b2[u];
        }
    }
}

// ---------------- score + partial context (flash-style) ----------------
// 512 blocks: b = bid>>4, tile = bid&15, t0 = tile*128. 512 threads = 8 waves, 2(M) x 4(N) grid;
// wave tile 64x128 (4 m-frags x 8 n-frags, acc=128). K-loop BK=32 (16 steps), DOUBLE-BUFFERED:
// per step issue next-step DMA first, then ds_read+MFMA current buffer, one __syncthreads
// (vmcnt(0)+lgkmcnt(0) drain + barrier) per step. LDS chunk slots XOR-swizzled:
//   A slot(r,cc)=r*8+(cc^(r&7))        fp32x4 chunks, 8/row   (2-way on read = free)
//   B slot(u,kc)=u*4+(kc^((u>>1)&3))   bf16x8 chunks, 4/row   (2-way on read = free)
// Epilogue: tanh+V dot -> 128 raw scores -> block max m, e_t, l -> partial ctx[d]=sum_t e_t*full[t,d]
// from the L2-hot tile. Writes ctx[bid][512], m_arr[bid], l_arr[bid].
__global__ __launch_bounds__(512) void score_kernel(const float* __restrict__ full,
                                                    const short* __restrict__ W1T,
                                                    const float* __restrict__ h2,
                                                    const float* __restrict__ V,
                                                    float* __restrict__ ctx,
                                                    float* __restrict__ m_arr,
                                                    float* __restrict__ l_arr) {
    __shared__ __align__(16) float a32[2][128 * BKK];    // 2 x 16 KB (1024 chunks each)
    __shared__ __align__(16) short blds[2][512 * BKK];   // 2 x 32 KB (2048 chunks each)
    __shared__ float red64[8][64];
    __shared__ float esc[128];
    __shared__ float sred[8];
    __shared__ __align__(16) float red4[4][128][4];      // 8 KB

    const int bid = blockIdx.x;
    const int b    = bid >> 4;
    const int t0   = (bid & 15) << 7;
    const int tid  = threadIdx.x;
    const int w    = tid >> 6;
    const int lane = tid & 63;
    const int quad = lane >> 4;
    const int col  = lane & 15;
    const int wm   = w >> 2;
    const int wn   = w & 3;

    f32x4 acc[4][8];
#pragma unroll
    for (int i = 0; i < 4; ++i)
#pragma unroll
        for (int j = 0; j < 8; ++j) acc[i][j] = (f32x4){0.f, 0.f, 0.f, 0.f};

    const size_t fullbase = (size_t)(b * TT + t0) * DD;

    // DMA one K-step into buffer `bufidx`. A: 1024 fp32x4 chunks (2 issues/thread);
    // B: 2048 bf16x8 chunks (4 issues/thread). Sources pre-swizzled so linear LDS dest
    // lands at the swizzled slot (global_load_lds writes base + lane*16).
#define STAGE(bufidx, koidx) do {                                                     \
        _Pragma("unroll")                                                             \
        for (int i = 0; i < 2; ++i) {                                                 \
            const int sb = w * 128 + i * 64;                                          \
            const int s  = sb + lane;                                                 \
            const int r  = s >> 3;                                                    \
            const int cc = (s & 7) ^ (r & 7);                                         \
            const float* g = &full[fullbase + (size_t)r * DD + (koidx) * BKK + cc * 4]; \
            __builtin_amdgcn_global_load_lds(                                         \
                (const __attribute__((address_space(1))) void*)g,                     \
                (__attribute__((address_space(3))) void*)&a32[bufidx][sb * 4], 16, 0, 0); \
        }                                                                             \
        _Pragma("unroll")                                                             \
        for (int i = 0; i < 4; ++i) {                                                 \
            const int sb = w * 256 + i * 64;                                          \
            const int s  = sb + lane;                                                 \
            const int u  = s >> 2;                                                    \
            const int kc = (s & 3) ^ ((u >> 1) & 3);                                  \
            const short* g = &W1T[(size_t)u * DD + (koidx) * BKK + kc * 8];           \
            __builtin_amdgcn_global_load_lds(                                         \
                (const __attribute__((address_space(1))) void*)g,                     \
                (__attribute__((address_space(3))) void*)&blds[bufidx][sb * 8], 16, 0, 0); \
        }                                                                             \
    } while (0)

    STAGE(0, 0);
    __syncthreads();          // vmcnt(0) drain + barrier: buf0 ready

    int cur = 0;
    for (int ko = 0; ko < KSTEPS; ++ko) {
        if (ko < KSTEPS - 1) STAGE(cur ^ 1, ko + 1);   // prefetch next step (overlaps MFMA below)

        bf16x8 af[4];
#pragma unroll
        for (int mt = 0; mt < 4; ++mt) {
            const int r  = wm * 64 + mt * 16 + col;
            const int c0 = quad * 2;
            const f32x4 lo = *(const f32x4*)&a32[cur][(r * 8 + (c0 ^ (r & 7))) * 4];
            const f32x4 hi = *(const f32x4*)&a32[cur][(r * 8 + ((c0 + 1) ^ (r & 7))) * 4];
            af[mt] = (bf16x8){f2bf(lo.x), f2bf(lo.y), f2bf(lo.z), f2bf(lo.w),
                              f2bf(hi.x), f2bf(hi.y), f2bf(hi.z), f2bf(hi.w)};
        }
#pragma unroll
        for (int nt = 0; nt < 8; ++nt) {
            const int u = wn * 128 + nt * 16 + col;
            const bf16x8 bf = *(const bf16x8*)&blds[cur][(u * 4 + (quad ^ ((u >> 1) & 3))) * 8];
#pragma unroll
            for (int mt = 0; mt < 4; ++mt)
                acc[mt][nt] = __builtin_amdgcn_mfma_f32_16x16x32_bf16(af[mt], bf, acc[mt][nt], 0, 0, 0);
        }
        __syncthreads();      // drains this step's ds_reads AND next step's DMA
        cur ^= 1;
    }
#undef STAGE

    // ---- raw scores: tanh + V-dot, reduce over this wave's 128 u, then over wn ----
    float srow[16];
#pragma unroll
    for (int i = 0; i < 16; ++i) srow[i] = 0.f;
#pragma unroll
    for (int nt = 0; nt < 8; ++nt) {
        const int u = wn * 128 + nt * 16 + col;
        const float hv = h2[b * UU + u];
        const float vv = V[u];
#pragma unroll
        for (int mt = 0; mt < 4; ++mt)
#pragma unroll
            for (int r = 0; r < 4; ++r)
                srow[mt * 4 + r] += fast_tanh(acc[mt][nt][r] + hv) * vv;
    }
#pragma unroll
    for (int off = 1; off < 16; off <<= 1) {
#pragma unroll
        for (int i = 0; i < 16; ++i) srow[i] += __shfl_xor(srow[i], off, 64);
    }
    if (col == 0) {
#pragma unroll
        for (int mt = 0; mt < 4; ++mt)
#pragma unroll
            for (int r = 0; r < 4; ++r)
                red64[w][mt * 16 + quad * 4 + r] = srow[mt * 4 + r];
    }
    __syncthreads();

    // ---- softmax stats over the 128 rows (threads 0..127 hold row tid) ----
    float sv = 0.f;
    if (tid < 128) {
        const int wmX = tid >> 6, rr = tid & 63;
        sv = red64[wmX * 4 + 0][rr] + red64[wmX * 4 + 1][rr] +
             red64[wmX * 4 + 2][rr] + red64[wmX * 4 + 3][rr];
        float mv = sv;
#pragma unroll
        for (int off = 1; off < 64; off <<= 1) mv = fmaxf(mv, __shfl_xor(mv, off, 64));
        if (lane == 0) sred[w] = mv;
    }
    __syncthreads();
    const float M = fmaxf(sred[0], sred[1]);
    if (tid < 128) {
        float e = __expf(sv - M);
        esc[tid] = e;
#pragma unroll
        for (int off = 1; off < 64; off <<= 1) e += __shfl_xor(e, off, 64);
        if (lane == 0) sred[4 + w] = e;
    }
    __syncthreads();
    if (tid == 0) { m_arr[bid] = M; l_arr[bid] = sred[4] + sred[5]; }

    // ---- partial context from the (L2-hot) tile: ctx[d] = sum_t esc[t] * full[t,d] ----
    const int c  = tid & 127;             // float4 column, d = c*4
    const int tp = tid >> 7;              // t residue mod 4
    float ax = 0.f, ay = 0.f, az = 0.f, aw = 0.f;
#pragma unroll 4
    for (int i = 0; i < 32; ++i) {
        const int t = i * 4 + tp;
        const float4 v = *(const float4*)&full[fullbase + (size_t)t * DD + c * 4];
        const float e = esc[t];
        ax += e * v.x; ay += e * v.y; az += e * v.z; aw += e * v.w;
    }
    *(float4*)&red4[tp][c][0] = make_float4(ax, ay, az, aw);
    __syncthreads();
    if (tp == 0) {
        const float4 p0 = *(const float4*)&red4[0][c][0];
        const float4 p1 = *(const float4*)&red4[1][c][0];
        const float4 p2 = *(const float4*)&red4[2][c][0];
        const float4 p3 = *(const float4*)&red4[3][c][0];
        float4 s = make_float4(p0.x + p1.x + p2.x + p3.x,
                               p0.y + p1.y + p2.y + p3.y,
                               p0.z + p1.z + p2.z + p3.z,
                               p0.w + p1.w + p2.w + p3.w);
        *(float4*)&ctx[(size_t)bid * DD + c * 4] = s;
    }
}

// ---------------- combine: out[b,d] = sum_i w_i*ctx[b,i,d] / sum_i w_i*l_i, w_i = e^{m_i - M} ----------------
__global__ __launch_bounds__(256) void combine_kernel(const float* __restrict__ ctx,
                                                      const float* __restrict__ m_arr,
                                                      const float* __restrict__ l_arr,
                                                      float* __restrict__ out) {
    const int b = blockIdx.x;
    const int tid = threadIdx.x;
    __shared__ float wgt[16];
    __shared__ float linv;
    if (tid == 0) {
        float M = -1e30f;
#pragma unroll
        for (int i = 0; i < 16; ++i) M = fmaxf(M, m_arr[b * 16 + i]);
        float l = 0.f;
#pragma unroll
        for (int i = 0; i < 16; ++i) {
            wgt[i] = __expf(m_arr[b * 16 + i] - M);
            l += wgt[i] * l_arr[b * 16 + i];
        }
        linv = 1.f / l;
    }
    __syncthreads();
    float s0 = 0.f, s1 = 0.f;
#pragma unroll
    for (int i = 0; i < 16; ++i) {
        const float wi = wgt[i];
        const float* cp = &ctx[(size_t)(b * 16 + i) * DD + tid * 2];
        s0 += wi * cp[0];
        s1 += wi * cp[1];
    }
    out[b * DD + tid * 2]     = s0 * linv;
    out[b * DD + tid * 2 + 1] = s1 * linv;
}

extern "C" void kernel_launch(void* const* d_in, const int* in_sizes, int n_in,
                              void* d_out, int out_size, void* d_ws, size_t ws_size,
                              hipStream_t stream) {
    const float* full = (const float*)d_in[0];
    const float* last = (const float*)d_in[1];
    const float* W1   = (const float*)d_in[2];
    const float* b1   = (const float*)d_in[3];
    const float* W2   = (const float*)d_in[4];
    const float* b2   = (const float*)d_in[5];
    const float* V    = (const float*)d_in[6];
    // d_in[7] = bV: softmax-invariant, unused.

    float* out   = (float*)d_out;
    float* h2    = (float*)d_ws;                    // 16384 floats
    float* m_arr = h2 + (size_t)BB * UU;            // 512
    float* l_arr = m_arr + 512;                     // 512
    float* ctx   = l_arr + 512;                     // 32*16*512 = 262144
    short* W1T   = (short*)(ctx + (size_t)BB * 16 * DD);  // U*D bf16

    prep_kernel<<<384, 256, 0, stream>>>(W1, W1T, last, W2, b1, b2, h2);
    score_kernel<<<BB * 16, 512, 0, stream>>>(full, W1T, h2, V, ctx, m_arr, l_arr);
    combine_kernel<<<BB, 256, 0, stream>>>(ctx, m_arr, l_arr, out);
}

// Round 2
// 259.863 us; speedup vs baseline: 1.0406x; 1.0191x over previous
//
#include <hip/hip_runtime.h>
#include <math.h>

// Attention pooling: context[b,d] = sum_t softmax_t( V . tanh(full[b,t,:]@W1 + last[b,:]@W2 + b1+b2) ) * full[b,t,d]
// B=32 T=2048 D=512 U=512, fp32 in/out. bV softmax-invariant -> dropped; b1+b2 folded into h2.
// R9: counted-vmcnt pipeline (guide T4). R8's __syncthreads drained vmcnt(0) each step, serializing
//     the 48KB/step staging with compute (observed ~3100cy/step vs ~1600cy stream floor). Now:
//     ds_read cur -> lgkmcnt(0)+sched_barrier -> s_barrier -> STAGE(cur, ko+2) -> MFMA ->
//     s_waitcnt vmcnt(6) -> s_barrier. Loads stay in flight across barriers (never drained to 0
//     in the main loop); each step's loads get a full step of landing slack.
// ws (floats): h2 [B*U] @0, m_arr [512] @16384, l_arr [512] @16896, ctx [B*16*D] @17408,
//              W1T [U*D] bf16 @ float-offset 279552. Total ~1.64 MB.

#define BB 32
#define TT 2048
#define DD 512
#define UU 512
#define BKK 32
#define KSTEPS 16

typedef short bf16x8 __attribute__((ext_vector_type(8)));
typedef float f32x4  __attribute__((ext_vector_type(4)));

static __device__ __forceinline__ short f2bf(float f) {
    unsigned x = __float_as_uint(f);
    return (short)((x + 0x7fffu + ((x >> 16) & 1u)) >> 16);   // RNE
}

static __device__ __forceinline__ float fast_tanh(float x) {
    float e = __expf(2.f * x);
    return 1.f - 2.f * __builtin_amdgcn_rcpf(e + 1.f);
}

// ---------------- prep ----------------
// blocks [0,256): W1T[u][d] = bf16(W1[d][u]) tile-transposed
// blocks [256,384): h2 slice — block owns (b, 128-u-slice); threads d-split x2 + LDS combine
__global__ __launch_bounds__(256) void prep_kernel(const float* __restrict__ W1,
                                                   short* __restrict__ W1T,
                                                   const float* __restrict__ last,
                                                   const float* __restrict__ W2,
                                                   const float* __restrict__ b1,
                                                   const float* __restrict__ b2,
                                                   float* __restrict__ h2) {
    __shared__ float tile[32][33];
    __shared__ float ls[DD];
    __shared__ float part[256];
    const int bid = blockIdx.x;
    const int tid = threadIdx.x;
    if (bid < 256) {
        const int tr = (bid >> 4) << 5;   // d-block origin
        const int tc = (bid & 15) << 5;   // u-block origin
#pragma unroll
        for (int p = 0; p < 4; ++p) {
            const int r = p * 8 + (tid >> 5), c = tid & 31;
            tile[r][c] = W1[(size_t)(tr + r) * UU + tc + c];
        }
        __syncthreads();
#pragma unroll
        for (int p = 0; p < 4; ++p) {
            const int r = p * 8 + (tid >> 5), c = tid & 31;    // r=u-local, c=d-local
            W1T[(size_t)(tc + r) * DD + tr + c] = f2bf(tile[c][r]);
        }
    } else {
        const int b2i = bid - 256;
        const int b  = b2i >> 2;
        const int u0 = (b2i & 3) << 7;
        for (int i = tid; i < DD; i += 256) ls[i] = last[b * DD + i];
        __syncthreads();
        const int uu = tid & 127;
        const int dh = tid >> 7;
        float acc = 0.f;
#pragma unroll 8
        for (int d = dh * 256; d < dh * 256 + 256; ++d)
            acc += ls[d] * W2[d * UU + u0 + uu];
        part[tid] = acc;
        __syncthreads();
        if (tid < 128) {
            const int u = u0 + tid;
            h2[b * UU + u] = part[tid] + part[tid + 128] + b1[u] + b2[u];
        }
    }
}

// ---------------- score + partial context (flash-style) ----------------
// 512 blocks: b = bid>>4, tile = bid&15, t0 = tile*128. 512 threads = 8 waves, 2(M) x 4(N) grid;
// wave tile 64x128 (4 m-frags x 8 n-frags, acc=128). K-loop BK=32 (16 steps), double-buffered with
// counted vmcnt (see header). LDS chunk slots XOR-swizzled:
//   A slot(r,cc)=r*8+(cc^(r&7))        fp32x4 chunks, 8/row   (2-way on read = free)
//   B slot(u,kc)=u*4+(kc^((u>>1)&3))   bf16x8 chunks, 4/row   (2-way on read = free)
// Epilogue: tanh+V dot -> 128 raw scores -> block max m, e_t, l -> partial ctx[d]=sum_t e_t*full[t,d]
// from the L2-hot tile. Writes ctx[bid][512], m_arr[bid], l_arr[bid].
__global__ __launch_bounds__(512) void score_kernel(const float* __restrict__ full,
                                                    const short* __restrict__ W1T,
                                                    const float* __restrict__ h2,
                                                    const float* __restrict__ V,
                                                    float* __restrict__ ctx,
                                                    float* __restrict__ m_arr,
                                                    float* __restrict__ l_arr) {
    __shared__ __align__(16) float a32[2][128 * BKK];    // 2 x 16 KB (1024 chunks each)
    __shared__ __align__(16) short blds[2][512 * BKK];   // 2 x 32 KB (2048 chunks each)
    __shared__ float red64[8][64];
    __shared__ float esc[128];
    __shared__ float sred[8];
    __shared__ __align__(16) float red4[4][128][4];      // 8 KB

    const int bid = blockIdx.x;
    const int b    = bid >> 4;
    const int t0   = (bid & 15) << 7;
    const int tid  = threadIdx.x;
    const int w    = tid >> 6;
    const int lane = tid & 63;
    const int quad = lane >> 4;
    const int col  = lane & 15;
    const int wm   = w >> 2;
    const int wn   = w & 3;

    f32x4 acc[4][8];
#pragma unroll
    for (int i = 0; i < 4; ++i)
#pragma unroll
        for (int j = 0; j < 8; ++j) acc[i][j] = (f32x4){0.f, 0.f, 0.f, 0.f};

    const size_t fullbase = (size_t)(b * TT + t0) * DD;

    // DMA one K-step into buffer `bufidx`. A: 1024 fp32x4 chunks (2 issues/thread);
    // B: 2048 bf16x8 chunks (4 issues/thread). 6 wave-load-instrs total per STAGE.
    // Sources pre-swizzled so linear LDS dest lands at the swizzled slot.
#define STAGE(bufidx, koidx) do {                                                     \
        _Pragma("unroll")                                                             \
        for (int i = 0; i < 2; ++i) {                                                 \
            const int sb = w * 128 + i * 64;                                          \
            const int s  = sb + lane;                                                 \
            const int r  = s >> 3;                                                    \
            const int cc = (s & 7) ^ (r & 7);                                         \
            const float* g = &full[fullbase + (size_t)r * DD + (koidx) * BKK + cc * 4]; \
            __builtin_amdgcn_global_load_lds(                                         \
                (const __attribute__((address_space(1))) void*)g,                     \
                (__attribute__((address_space(3))) void*)&a32[bufidx][sb * 4], 16, 0, 0); \
        }                                                                             \
        _Pragma("unroll")                                                             \
        for (int i = 0; i < 4; ++i) {                                                 \
            const int sb = w * 256 + i * 64;                                          \
            const int s  = sb + lane;                                                 \
            const int u  = s >> 2;                                                    \
            const int kc = (s & 3) ^ ((u >> 1) & 3);                                  \
            const short* g = &W1T[(size_t)u * DD + (koidx) * BKK + kc * 8];           \
            __builtin_amdgcn_global_load_lds(                                         \
                (const __attribute__((address_space(1))) void*)g,                     \
                (__attribute__((address_space(3))) void*)&blds[bufidx][sb * 8], 16, 0, 0); \
        }                                                                             \
    } while (0)

    // Prologue: fill both buffers; wait only for step0 (step1 stays in flight).
    STAGE(0, 0);
    STAGE(1, 1);
    asm volatile("s_waitcnt vmcnt(6)" ::: "memory");
    __builtin_amdgcn_s_barrier();

    int cur = 0;
    for (int ko = 0; ko < KSTEPS; ++ko) {
        // ---- phase 1: ds_read everything this step needs from buf[cur] ----
        f32x4 alo[4], ahi[4];
        bf16x8 bfr[8];
#pragma unroll
        for (int mt = 0; mt < 4; ++mt) {
            const int r  = wm * 64 + mt * 16 + col;
            const int c0 = quad * 2;
            alo[mt] = *(const f32x4*)&a32[cur][(r * 8 + (c0 ^ (r & 7))) * 4];
            ahi[mt] = *(const f32x4*)&a32[cur][(r * 8 + ((c0 + 1) ^ (r & 7))) * 4];
        }
#pragma unroll
        for (int nt = 0; nt < 8; ++nt) {
            const int u = wn * 128 + nt * 16 + col;
            bfr[nt] = *(const bf16x8*)&blds[cur][(u * 4 + (quad ^ ((u >> 1) & 3))) * 8];
        }
        asm volatile("s_waitcnt lgkmcnt(0)" ::: "memory");
        __builtin_amdgcn_sched_barrier(0);          // rule 18: pin reg-consumers below the wait
        __builtin_amdgcn_s_barrier();               // all waves done reading buf[cur]

        // ---- phase 2: overwrite buf[cur] with step ko+2 (loads fly across next step) ----
        if (ko + 2 < KSTEPS) STAGE(cur, ko + 2);

        // ---- phase 3: convert + MFMA (register-only, overlaps in-flight loads) ----
        bf16x8 af[4];
#pragma unroll
        for (int mt = 0; mt < 4; ++mt)
            af[mt] = (bf16x8){f2bf(alo[mt].x), f2bf(alo[mt].y), f2bf(alo[mt].z), f2bf(alo[mt].w),
                              f2bf(ahi[mt].x), f2bf(ahi[mt].y), f2bf(ahi[mt].z), f2bf(ahi[mt].w)};
#pragma unroll
        for (int nt = 0; nt < 8; ++nt)
#pragma unroll
            for (int mt = 0; mt < 4; ++mt)
                acc[mt][nt] = __builtin_amdgcn_mfma_f32_16x16x32_bf16(af[mt], bfr[nt], acc[mt][nt], 0, 0, 0);

        // ---- phase 4: counted wait — only require step ko+1's loads landed ----
        if (ko < KSTEPS - 2) {
            asm volatile("s_waitcnt vmcnt(6)" ::: "memory");
        } else if (ko == KSTEPS - 2) {
            asm volatile("s_waitcnt vmcnt(0)" ::: "memory");
        }
        if (ko < KSTEPS - 1) __builtin_amdgcn_s_barrier();
        cur ^= 1;
    }
#undef STAGE

    // ---- raw scores: tanh + V-dot, reduce over this wave's 128 u, then over wn ----
    float srow[16];
#pragma unroll
    for (int i = 0; i < 16; ++i) srow[i] = 0.f;
#pragma unroll
    for (int nt = 0; nt < 8; ++nt) {
        const int u = wn * 128 + nt * 16 + col;
        const float hv = h2[b * UU + u];
        const float vv = V[u];
#pragma unroll
        for (int mt = 0; mt < 4; ++mt)
#pragma unroll
            for (int r = 0; r < 4; ++r)
                srow[mt * 4 + r] += fast_tanh(acc[mt][nt][r] + hv) * vv;
    }
#pragma unroll
    for (int off = 1; off < 16; off <<= 1) {
#pragma unroll
        for (int i = 0; i < 16; ++i) srow[i] += __shfl_xor(srow[i], off, 64);
    }
    if (col == 0) {
#pragma unroll
        for (int mt = 0; mt < 4; ++mt)
#pragma unroll
            for (int r = 0; r < 4; ++r)
                red64[w][mt * 16 + quad * 4 + r] = srow[mt * 4 + r];
    }
    __syncthreads();

    // ---- softmax stats over the 128 rows (threads 0..127 hold row tid) ----
    float sv = 0.f;
    if (tid < 128) {
        const int wmX = tid >> 6, rr = tid & 63;
        sv = red64[wmX * 4 + 0][rr] + red64[wmX * 4 + 1][rr] +
             red64[wmX * 4 + 2][rr] + red64[wmX * 4 + 3][rr];
        float mv = sv;
#pragma unroll
        for (int off = 1; off < 64; off <<= 1) mv = fmaxf(mv, __shfl_xor(mv, off, 64));
        if (lane == 0) sred[w] = mv;
    }
    __syncthreads();
    const float M = fmaxf(sred[0], sred[1]);
    if (tid < 128) {
        float e = __expf(sv - M);
        esc[tid] = e;
#pragma unroll
        for (int off = 1; off < 64; off <<= 1) e += __shfl_xor(e, off, 64);
        if (lane == 0) sred[4 + w] = e;
    }
    __syncthreads();
    if (tid == 0) { m_arr[bid] = M; l_arr[bid] = sred[4] + sred[5]; }

    // ---- partial context from the (L2-hot) tile: ctx[d] = sum_t esc[t] * full[t,d] ----
    const int c  = tid & 127;             // float4 column, d = c*4
    const int tp = tid >> 7;              // t residue mod 4
    float ax = 0.f, ay = 0.f, az = 0.f, aw = 0.f;
#pragma unroll 4
    for (int i = 0; i < 32; ++i) {
        const int t = i * 4 + tp;
        const float4 v = *(const float4*)&full[fullbase + (size_t)t * DD + c * 4];
        const float e = esc[t];
        ax += e * v.x; ay += e * v.y; az += e * v.z; aw += e * v.w;
    }
    *(float4*)&red4[tp][c][0] = make_float4(ax, ay, az, aw);
    __syncthreads();
    if (tp == 0) {
        const float4 p0 = *(const float4*)&red4[0][c][0];
        const float4 p1 = *(const float4*)&red4[1][c][0];
        const float4 p2 = *(const float4*)&red4[2][c][0];
        const float4 p3 = *(const float4*)&red4[3][c][0];
        float4 s = make_float4(p0.x + p1.x + p2.x + p3.x,
                               p0.y + p1.y + p2.y + p3.y,
                               p0.z + p1.z + p2.z + p3.z,
                               p0.w + p1.w + p2.w + p3.w);
        *(float4*)&ctx[(size_t)bid * DD + c * 4] = s;
    }
}

// ---------------- combine: out[b,d] = sum_i w_i*ctx[b,i,d] / sum_i w_i*l_i, w_i = e^{m_i - M} ----------------
__global__ __launch_bounds__(256) void combine_kernel(const float* __restrict__ ctx,
                                                      const float* __restrict__ m_arr,
                                                      const float* __restrict__ l_arr,
                                                      float* __restrict__ out) {
    const int b = blockIdx.x;
    const int tid = threadIdx.x;
    __shared__ float wgt[16];
    __shared__ float linv;
    if (tid == 0) {
        float M = -1e30f;
#pragma unroll
        for (int i = 0; i < 16; ++i) M = fmaxf(M, m_arr[b * 16 + i]);
        float l = 0.f;
#pragma unroll
        for (int i = 0; i < 16; ++i) {
            wgt[i] = __expf(m_arr[b * 16 + i] - M);
            l += wgt[i] * l_arr[b * 16 + i];
        }
        linv = 1.f / l;
    }
    __syncthreads();
    float s0 = 0.f, s1 = 0.f;
#pragma unroll
    for (int i = 0; i < 16; ++i) {
        const float wi = wgt[i];
        const float* cp = &ctx[(size_t)(b * 16 + i) * DD + tid * 2];
        s0 += wi * cp[0];
        s1 += wi * cp[1];
    }
    out[b * DD + tid * 2]     = s0 * linv;
    out[b * DD + tid * 2 + 1] = s1 * linv;
}

extern "C" void kernel_launch(void* const* d_in, const int* in_sizes, int n_in,
                              void* d_out, int out_size, void* d_ws, size_t ws_size,
                              hipStream_t stream) {
    const float* full = (const float*)d_in[0];
    const float* last = (const float*)d_in[1];
    const float* W1   = (const float*)d_in[2];
    const float* b1   = (const float*)d_in[3];
    const float* W2   = (const float*)d_in[4];
    const float* b2   = (const float*)d_in[5];
    const float* V    = (const float*)d_in[6];
    // d_in[7] = bV: softmax-invariant, unused.

    float* out   = (float*)d_out;
    float* h2    = (float*)d_ws;                    // 16384 floats
    float* m_arr = h2 + (size_t)BB * UU;            // 512
    float* l_arr = m_arr + 512;                     // 512
    float* ctx   = l_arr + 512;                     // 32*16*512 = 262144
    short* W1T   = (short*)(ctx + (size_t)BB * 16 * DD);  // U*D bf16

    prep_kernel<<<384, 256, 0, stream>>>(W1, W1T, last, W2, b1, b2, h2);
    score_kernel<<<BB * 16, 512, 0, stream>>>(full, W1T, h2, V, ctx, m_arr, l_arr);
    combine_kernel<<<BB, 256, 0, stream>>>(ctx, m_arr, l_arr, out);
}